// Round 2
// baseline (4561.856 us; speedup 1.0000x reference)
//
#include <hip/hip_runtime.h>
#include <hip/hip_bf16.h>

// SolveGradientsLST: least-squares gradient reconstruction on a graph.
// pos [N,2] f32, edge_index [2,E] i32, field [N,F=4] f32 -> out [F,N,2] f32.
//
// Pass 1 (edges): scatter-add per-edge moment matrix (3 floats, symmetric 2x2)
//                 and RHS (2x4 = 8 floats) into a per-node accumulator struct
//                 of 16 floats (64B, single cache-line span) via f32 atomics.
// Pass 2 (nodes): 2x2 solve in f64 (f32 det = m00*m11 - m01^2 is
//                 rounding-noise-dominated for low-degree nodes), clip,
//                 write transposed [F,N,2] output.
//
// Accumulator layout per node (16 floats, 64B aligned):
//   [0] m00  [1] m01  [2] m11  [3] pad
//   [4..7]  V[0][0..3]  (dx0 * du_f)
//   [8..11] V[1][0..3]  (dx1 * du_f)
//   [12..15] pad

#define GRAD_LIMIT 30000.0f
#define EPS 1e-8

__global__ void edge_accum_kernel(const float2* __restrict__ pos,
                                  const int* __restrict__ rows,
                                  const int* __restrict__ cols,
                                  const float4* __restrict__ field,
                                  float* __restrict__ acc,   // [N,16]
                                  int E) {
    int e = blockIdx.x * blockDim.x + threadIdx.x;
    if (e >= E) return;

    int r = rows[e];
    int c = cols[e];

    float2 pr = pos[r];
    float2 pc = pos[c];
    float dx0 = pc.x - pr.x;
    float dx1 = pc.y - pr.y;

    float4 fr = field[r];
    float4 fc = field[c];
    float du0 = fc.x - fr.x;
    float du1 = fc.y - fr.y;
    float du2 = fc.z - fr.z;
    float du3 = fc.w - fr.w;

    float* a = acc + ((size_t)r << 4);
    atomicAdd(a + 0, dx0 * dx0);
    atomicAdd(a + 1, dx0 * dx1);
    atomicAdd(a + 2, dx1 * dx1);

    atomicAdd(a + 4, dx0 * du0);
    atomicAdd(a + 5, dx0 * du1);
    atomicAdd(a + 6, dx0 * du2);
    atomicAdd(a + 7, dx0 * du3);
    atomicAdd(a + 8, dx1 * du0);
    atomicAdd(a + 9, dx1 * du1);
    atomicAdd(a + 10, dx1 * du2);
    atomicAdd(a + 11, dx1 * du3);
}

__global__ void node_solve_kernel(const float* __restrict__ acc,
                                  float* __restrict__ out,  // [F,N,2]
                                  int N) {
    int n = blockIdx.x * blockDim.x + threadIdx.x;
    if (n >= N) return;

    const float* a = acc + ((size_t)n << 4);

    // f64 solve on the f32-accumulated moments: deterministic and accurate.
    double m00 = (double)a[0] + EPS;
    double m01 = (double)a[1];
    double m11 = (double)a[2] + EPS;
    double det = m00 * m11 - m01 * m01;
    double inv_det = 1.0 / det;
    double i00 =  m11 * inv_det;
    double i01 = -m01 * inv_det;
    double i11 =  m00 * inv_det;

    float4 v0 = *reinterpret_cast<const float4*>(a + 4);  // V[0][0..3]
    float4 v1 = *reinterpret_cast<const float4*>(a + 8);  // V[1][0..3]

    const float vf0[4] = {v0.x, v0.y, v0.z, v0.w};
    const float vf1[4] = {v1.x, v1.y, v1.z, v1.w};
    float g0[4], g1[4];
#pragma unroll
    for (int f = 0; f < 4; ++f) {
        double ga = i00 * (double)vf0[f] + i01 * (double)vf1[f];
        double gb = i01 * (double)vf0[f] + i11 * (double)vf1[f];
        g0[f] = fminf(fmaxf((float)ga, -GRAD_LIMIT), GRAD_LIMIT);
        g1[f] = fminf(fmaxf((float)gb, -GRAD_LIMIT), GRAD_LIMIT);
    }

    // out[f][n][i] = grads[n][i][f]; per-f float2 store, coalesced over n.
#pragma unroll
    for (int f = 0; f < 4; ++f) {
        float2 o;
        o.x = g0[f];
        o.y = g1[f];
        *reinterpret_cast<float2*>(out + (size_t)f * N * 2 + (size_t)n * 2) = o;
    }
}

extern "C" void kernel_launch(void* const* d_in, const int* in_sizes, int n_in,
                              void* d_out, int out_size, void* d_ws, size_t ws_size,
                              hipStream_t stream) {
    const float2* pos = (const float2*)d_in[0];
    const int* edge_index = (const int*)d_in[1];
    const float4* field = (const float4*)d_in[2];
    float* out = (float*)d_out;

    const int N = in_sizes[0] / 2;
    const int E = in_sizes[1] / 2;

    const int* rows = edge_index;       // edge_index[0, :]
    const int* cols = edge_index + E;   // edge_index[1, :]

    float* acc = (float*)d_ws;          // [N,16] floats = 32 MB

    // Zero the accumulators (harness re-poisons d_ws to 0xAA before launches).
    hipMemsetAsync(acc, 0, (size_t)N * 16 * sizeof(float), stream);

    {
        int threads = 256;
        int blocks = (E + threads - 1) / threads;
        edge_accum_kernel<<<blocks, threads, 0, stream>>>(pos, rows, cols, field,
                                                          acc, E);
    }
    {
        int threads = 256;
        int blocks = (N + threads - 1) / threads;
        node_solve_kernel<<<blocks, threads, 0, stream>>>(acc, out, N);
    }
}

// Round 3
// 1351.308 us; speedup vs baseline: 3.3759x; 3.3759x over previous
//
#include <hip/hip_runtime.h>
#include <hip/hip_bf16.h>

// SolveGradientsLST via CSR counting sort — zero float atomics.
//
// R2 measured: 88M f32 atomics = 4.47ms, 2.82GB atomic write-back (32B/atomic
// RMW sector), VALUBusy 0.14%. Atomic COUNT is the cost currency (line-packing
// the accumulator did nothing). So: build CSR (2 int atomics/edge total),
// then accumulate per-node in registers with no atomics at all.
//
// Pipeline:
//   K0  memset cnt[N] = 0                     (2 MB)
//   K1  cnt[row[e]]++                         (8M int atomics)
//   K2a block sums of cnt (chunks of 2048)
//   K2b single-block exclusive scan of block sums
//   K2c per-chunk exclusive scan + base -> offsets (in-place over cnt)
//   K3  slot = offsets[row[e]]++ (atomic); csr_col[slot] = col[e]
//       (post-scatter offsets[n] == END of node n's range)
//   K4  per-node: accumulate M (3) + V (8) in registers over CSR range,
//       f64 2x2 solve, clip, write [F,N,2]

#define GRAD_LIMIT 30000.0f
#define EPS 1e-8

// ---------------- K1: histogram ----------------
__global__ void count_kernel(const int* __restrict__ rows, int* __restrict__ cnt,
                             int E) {
    int stride = gridDim.x * blockDim.x;
    int i0 = blockIdx.x * blockDim.x + threadIdx.x;
    int E4 = E >> 2;
    const int4* rows4 = (const int4*)rows;
    for (int i = i0; i < E4; i += stride) {
        int4 r = rows4[i];
        atomicAdd(&cnt[r.x], 1);
        atomicAdd(&cnt[r.y], 1);
        atomicAdd(&cnt[r.z], 1);
        atomicAdd(&cnt[r.w], 1);
    }
    // tail
    for (int e = (E4 << 2) + i0; e < E; e += stride) atomicAdd(&cnt[rows[e]], 1);
}

// ---------------- K2a: per-chunk sums (chunk = 2048 = 512 thr x 4) ----------
__global__ void block_sum_kernel(const int* __restrict__ cnt,
                                 int* __restrict__ partials, int N) {
    __shared__ int sdata[512];
    int t = threadIdx.x;
    int base = blockIdx.x * 2048 + t * 4;
    int s = 0;
#pragma unroll
    for (int k = 0; k < 4; ++k) {
        int i = base + k;
        if (i < N) s += cnt[i];
    }
    sdata[t] = s;
    __syncthreads();
    for (int d = 256; d > 0; d >>= 1) {
        if (t < d) sdata[t] += sdata[t + d];
        __syncthreads();
    }
    if (t == 0) partials[blockIdx.x] = sdata[0];
}

// ---------------- K2b: single-block exclusive scan of partials (nb<=1024) ---
__global__ void scan_partials_kernel(int* __restrict__ partials, int nb) {
    __shared__ int sdata[1024];
    int t = threadIdx.x;
    int v = (t < nb) ? partials[t] : 0;
    sdata[t] = v;
    __syncthreads();
    for (int d = 1; d < 1024; d <<= 1) {
        int x = (t >= d) ? sdata[t - d] : 0;
        __syncthreads();
        sdata[t] += x;
        __syncthreads();
    }
    if (t < nb) partials[t] = sdata[t] - v;  // exclusive
}

// ---------------- K2c: chunk-local scan + base -> offsets (in-place) --------
__global__ void scan_offsets_kernel(int* __restrict__ cnt,
                                    const int* __restrict__ partials, int N) {
    __shared__ int sdata[512];
    int t = threadIdx.x;
    int base = blockIdx.x * 2048 + t * 4;

    int c0 = 0, c1 = 0, c2 = 0, c3 = 0;
    if (base + 3 < N) {
        int4 c = *reinterpret_cast<const int4*>(cnt + base);
        c0 = c.x; c1 = c.y; c2 = c.z; c3 = c.w;
    } else {
        if (base < N) c0 = cnt[base];
        if (base + 1 < N) c1 = cnt[base + 1];
        if (base + 2 < N) c2 = cnt[base + 2];
    }
    int s = c0 + c1 + c2 + c3;
    sdata[t] = s;
    __syncthreads();
    for (int d = 1; d < 512; d <<= 1) {
        int x = (t >= d) ? sdata[t - d] : 0;
        __syncthreads();
        sdata[t] += x;
        __syncthreads();
    }
    int ex = sdata[t] - s + partials[blockIdx.x];  // exclusive prefix for elem 0

    int o0 = ex, o1 = ex + c0, o2 = o1 + c1, o3 = o2 + c2;
    if (base + 3 < N) {
        *reinterpret_cast<int4*>(cnt + base) = make_int4(o0, o1, o2, o3);
    } else {
        if (base < N) cnt[base] = o0;
        if (base + 1 < N) cnt[base + 1] = o1;
        if (base + 2 < N) cnt[base + 2] = o2;
    }
}

// ---------------- K3: scatter col into CSR order ----------------------------
__global__ void scatter_kernel(const int* __restrict__ rows,
                               const int* __restrict__ cols,
                               int* __restrict__ off,      // becomes END offsets
                               int* __restrict__ csr_col, int E) {
    int stride = gridDim.x * blockDim.x;
    int i0 = blockIdx.x * blockDim.x + threadIdx.x;
    int E4 = E >> 2;
    const int4* rows4 = (const int4*)rows;
    const int4* cols4 = (const int4*)cols;
    for (int i = i0; i < E4; i += stride) {
        int4 r = rows4[i];
        int4 c = cols4[i];
        csr_col[atomicAdd(&off[r.x], 1)] = c.x;
        csr_col[atomicAdd(&off[r.y], 1)] = c.y;
        csr_col[atomicAdd(&off[r.z], 1)] = c.z;
        csr_col[atomicAdd(&off[r.w], 1)] = c.w;
    }
    for (int e = (E4 << 2) + i0; e < E; e += stride)
        csr_col[atomicAdd(&off[rows[e]], 1)] = cols[e];
}

// ---------------- K4: per-node accumulate + f64 solve + store ---------------
__global__ void node_solve_kernel(const float2* __restrict__ pos,
                                  const float4* __restrict__ field,
                                  const int* __restrict__ end_off,
                                  const int* __restrict__ csr_col,
                                  float* __restrict__ out,  // [F,N,2]
                                  int N) {
    int n = blockIdx.x * blockDim.x + threadIdx.x;
    if (n >= N) return;

    int start = (n == 0) ? 0 : end_off[n - 1];
    int end = end_off[n];

    float2 pn = pos[n];
    float4 fn = field[n];

    float m00 = 0.f, m01 = 0.f, m11 = 0.f;
    float v00 = 0.f, v01 = 0.f, v02 = 0.f, v03 = 0.f;
    float v10 = 0.f, v11 = 0.f, v12 = 0.f, v13 = 0.f;

    for (int s = start; s < end; ++s) {
        int c = csr_col[s];
        float2 pc = pos[c];
        float4 fc = field[c];
        float dx0 = pc.x - pn.x;
        float dx1 = pc.y - pn.y;
        float du0 = fc.x - fn.x;
        float du1 = fc.y - fn.y;
        float du2 = fc.z - fn.z;
        float du3 = fc.w - fn.w;
        m00 = fmaf(dx0, dx0, m00);
        m01 = fmaf(dx0, dx1, m01);
        m11 = fmaf(dx1, dx1, m11);
        v00 = fmaf(dx0, du0, v00);
        v01 = fmaf(dx0, du1, v01);
        v02 = fmaf(dx0, du2, v02);
        v03 = fmaf(dx0, du3, v03);
        v10 = fmaf(dx1, du0, v10);
        v11 = fmaf(dx1, du1, v11);
        v12 = fmaf(dx1, du2, v12);
        v13 = fmaf(dx1, du3, v13);
    }

    // f64 2x2 solve: f32 det = m00*m11 - m01^2 is cancellation-dominated for
    // low-degree nodes; f64 on f32-accumulated moments is accurate + cheap.
    double M00 = (double)m00 + EPS;
    double M01 = (double)m01;
    double M11 = (double)m11 + EPS;
    double inv_det = 1.0 / (M00 * M11 - M01 * M01);
    double i00 = M11 * inv_det;
    double i01 = -M01 * inv_det;
    double i11 = M00 * inv_det;

    const float vf0[4] = {v00, v01, v02, v03};
    const float vf1[4] = {v10, v11, v12, v13};
#pragma unroll
    for (int f = 0; f < 4; ++f) {
        float ga = (float)(i00 * (double)vf0[f] + i01 * (double)vf1[f]);
        float gb = (float)(i01 * (double)vf0[f] + i11 * (double)vf1[f]);
        float2 o;
        o.x = fminf(fmaxf(ga, -GRAD_LIMIT), GRAD_LIMIT);
        o.y = fminf(fmaxf(gb, -GRAD_LIMIT), GRAD_LIMIT);
        *reinterpret_cast<float2*>(out + (size_t)f * N * 2 + (size_t)n * 2) = o;
    }
}

extern "C" void kernel_launch(void* const* d_in, const int* in_sizes, int n_in,
                              void* d_out, int out_size, void* d_ws, size_t ws_size,
                              hipStream_t stream) {
    const float2* pos = (const float2*)d_in[0];
    const int* edge_index = (const int*)d_in[1];
    const float4* field = (const float4*)d_in[2];
    float* out = (float*)d_out;

    const int N = in_sizes[0] / 2;
    const int E = in_sizes[1] / 2;

    const int* rows = edge_index;      // edge_index[0, :]
    const int* cols = edge_index + E;  // edge_index[1, :]

    // Workspace layout (ints): cnt/offsets [N] | partials [4096] | csr_col [E]
    int* cnt = (int*)d_ws;
    int* partials = cnt + N;
    int* csr_col = partials + 4096;

    const int nb = (N + 2047) / 2048;  // chunks of 2048 for the scan (nb<=1024)

    hipMemsetAsync(cnt, 0, (size_t)N * sizeof(int), stream);

    count_kernel<<<2048, 256, 0, stream>>>(rows, cnt, E);
    block_sum_kernel<<<nb, 512, 0, stream>>>(cnt, partials, N);
    scan_partials_kernel<<<1, 1024, 0, stream>>>(partials, nb);
    scan_offsets_kernel<<<nb, 512, 0, stream>>>(cnt, partials, N);
    scatter_kernel<<<2048, 256, 0, stream>>>(rows, cols, cnt, csr_col, E);
    node_solve_kernel<<<(N + 255) / 256, 256, 0, stream>>>(pos, field, cnt,
                                                           csr_col, out, N);
}

// Round 5
// 663.628 us; speedup vs baseline: 6.8741x; 2.0362x over previous
//
#include <hip/hip_runtime.h>
#include <hip/hip_bf16.h>

// SolveGradientsLST via two-level bucket binning + LDS accumulation.
// (Resubmission of R4 — bench infra timed out, no counters were produced.)
//
// R3 measured: scatter_kernel 685us (8M returning global atomics + 8M random
// 4B writes -> 502MB of 32B sectors), count_kernel ~8M more atomics,
// VALUBusy 0.2%. Global atomic COUNT is the cost; LDS atomics are ~free.
//
// Pipeline (buckets of 512 nodes, 977 buckets):
//   KA  per-block LDS histogram of row>>9  -> ~1M fire-and-forget global adds
//   KS  1-block scan of 977 bucket counts  -> bucket_start, cursor
//   KB  per-block LDS ranks (LDS returning atomics) + 1 returning global
//       atomic per (block,bucket); write packed payload (row&511)<<19 | col
//   KC  one block per bucket: accumulate M(3)+V(8) into LDS acc[512][13]
//       via ds_add_f32, then per-node f64 2x2 solve, clip, write [F,N,2]

#define GRAD_LIMIT 30000.0f
#define EPS 1e-8

#define NBUCKET_MAX 1024
#define BSHIFT 9
#define BSIZE 512                 // nodes per bucket
#define CHUNK 8192                // edges per block in KA/KB
#define BTHREADS 512
#define PER_THREAD (CHUNK / BTHREADS)   // 16
#define ACC_STRIDE 13             // 11 used + 2 pad; gcd(13,32)=1 spreads banks

// ---------------- KA: bucket histogram (LDS-aggregated) ----------------
__global__ void __launch_bounds__(BTHREADS)
bucket_count_kernel(const int* __restrict__ rows, int* __restrict__ bucket_cnt,
                    int E, int nbuckets) {
    __shared__ int hist[NBUCKET_MAX];
    for (int i = threadIdx.x; i < nbuckets; i += blockDim.x) hist[i] = 0;
    __syncthreads();

    int base = blockIdx.x * CHUNK;
    int lim = E - base;
    if (lim > CHUNK) lim = CHUNK;
    for (int k = threadIdx.x; k < lim; k += blockDim.x) {
        int r = rows[base + k];
        atomicAdd(&hist[r >> BSHIFT], 1);
    }
    __syncthreads();
    for (int i = threadIdx.x; i < nbuckets; i += blockDim.x) {
        int c = hist[i];
        if (c) atomicAdd(&bucket_cnt[i], c);   // fire-and-forget
    }
}

// ---------------- KS: single-block scan of bucket counts ----------------
__global__ void bucket_scan_kernel(const int* __restrict__ bucket_cnt,
                                   int* __restrict__ bucket_start,
                                   int* __restrict__ cursor, int nb) {
    __shared__ int s[NBUCKET_MAX];
    int t = threadIdx.x;
    int v = (t < nb) ? bucket_cnt[t] : 0;
    s[t] = v;
    __syncthreads();
    for (int d = 1; d < NBUCKET_MAX; d <<= 1) {
        int x = (t >= d) ? s[t - d] : 0;
        __syncthreads();
        s[t] += x;
        __syncthreads();
    }
    if (t < nb) {
        int ex = s[t] - v;     // exclusive prefix
        bucket_start[t] = ex;
        cursor[t] = ex;
    }
}

// ---------------- KB: scatter packed payload into bucket regions --------
__global__ void __launch_bounds__(BTHREADS)
bucket_scatter_kernel(const int* __restrict__ rows, const int* __restrict__ cols,
                      int* __restrict__ cursor, unsigned* __restrict__ payload,
                      int E, int nbuckets) {
    __shared__ int hist[NBUCKET_MAX];
    __shared__ int lbase[NBUCKET_MAX];
    for (int i = threadIdx.x; i < nbuckets; i += blockDim.x) hist[i] = 0;
    __syncthreads();

    int base = blockIdx.x * CHUNK;
    int lim = E - base;
    if (lim > CHUNK) lim = CHUNK;

    unsigned pk[PER_THREAD];
    int bl[PER_THREAD];   // (bucket<<13)|local_rank, or -1 if inactive
#pragma unroll
    for (int k = 0; k < PER_THREAD; ++k) {
        int idx = k * BTHREADS + threadIdx.x;   // coalesced per iteration
        if (idx < lim) {
            int e = base + idx;
            int r = rows[e];
            int c = cols[e];
            int b = r >> BSHIFT;
            int lr = atomicAdd(&hist[b], 1);    // LDS returning atomic (fast)
            pk[k] = ((unsigned)(r & (BSIZE - 1)) << 19) | (unsigned)c;  // c<2^19
            bl[k] = (b << 13) | lr;             // lr < 8192
        } else {
            bl[k] = -1;
        }
    }
    __syncthreads();
    // One returning global atomic per (block, nonzero bucket): ~1M total.
    for (int i = threadIdx.x; i < nbuckets; i += blockDim.x) {
        int c = hist[i];
        lbase[i] = c ? atomicAdd(&cursor[i], c) : 0;
    }
    __syncthreads();
#pragma unroll
    for (int k = 0; k < PER_THREAD; ++k) {
        if (bl[k] >= 0) {
            int b = bl[k] >> 13;
            int lr = bl[k] & 8191;
            payload[lbase[b] + lr] = pk[k];     // ~32B contiguous runs
        }
    }
}

// ---------------- KC: per-bucket LDS accumulate + f64 solve + store ----
__global__ void __launch_bounds__(BSIZE)
bucket_accum_solve_kernel(const float2* __restrict__ pos,
                          const float4* __restrict__ field,
                          const int* __restrict__ bucket_start,
                          const int* __restrict__ cursor,   // == bucket end
                          const unsigned* __restrict__ payload,
                          float* __restrict__ out,  // [F,N,2]
                          int N) {
    __shared__ float acc[BSIZE * ACC_STRIDE];   // 26.6 KB
    int b = blockIdx.x;
    int node0 = b << BSHIFT;

    for (int i = threadIdx.x; i < BSIZE * ACC_STRIDE; i += blockDim.x)
        acc[i] = 0.f;
    __syncthreads();

    int s0 = bucket_start[b];
    int s1 = cursor[b];
    for (int s = s0 + threadIdx.x; s < s1; s += blockDim.x) {
        unsigned p = payload[s];
        int c = (int)(p & 0x7FFFFu);
        int rl = (int)(p >> 19);
        int r = node0 + rl;

        float2 pr = pos[r];                 // 4KB window: L1-resident
        float2 pc = pos[c];                 // random: L2/L3
        float4 fr = field[r];
        float4 fc = field[c];
        float dx0 = pc.x - pr.x;
        float dx1 = pc.y - pr.y;
        float du0 = fc.x - fr.x;
        float du1 = fc.y - fr.y;
        float du2 = fc.z - fr.z;
        float du3 = fc.w - fr.w;

        float* a = acc + rl * ACC_STRIDE;
        atomicAdd(a + 0, dx0 * dx0);        // ds_add_f32, fire-and-forget
        atomicAdd(a + 1, dx0 * dx1);
        atomicAdd(a + 2, dx1 * dx1);
        atomicAdd(a + 3, dx0 * du0);
        atomicAdd(a + 4, dx0 * du1);
        atomicAdd(a + 5, dx0 * du2);
        atomicAdd(a + 6, dx0 * du3);
        atomicAdd(a + 7, dx1 * du0);
        atomicAdd(a + 8, dx1 * du1);
        atomicAdd(a + 9, dx1 * du2);
        atomicAdd(a + 10, dx1 * du3);
    }
    __syncthreads();

    int rl = threadIdx.x;   // blockDim == BSIZE: one node per thread
    int n = node0 + rl;
    if (n < N) {
        const float* a = acc + rl * ACC_STRIDE;
        // f64 2x2 solve: f32 det = m00*m11 - m01^2 is cancellation-dominated
        // for low-degree nodes.
        double M00 = (double)a[0] + EPS;
        double M01 = (double)a[1];
        double M11 = (double)a[2] + EPS;
        double inv_det = 1.0 / (M00 * M11 - M01 * M01);
        double i00 = M11 * inv_det;
        double i01 = -M01 * inv_det;
        double i11 = M00 * inv_det;

        const float vf0[4] = {a[3], a[4], a[5], a[6]};
        const float vf1[4] = {a[7], a[8], a[9], a[10]};
#pragma unroll
        for (int f = 0; f < 4; ++f) {
            float ga = (float)(i00 * (double)vf0[f] + i01 * (double)vf1[f]);
            float gb = (float)(i01 * (double)vf0[f] + i11 * (double)vf1[f]);
            float2 o;
            o.x = fminf(fmaxf(ga, -GRAD_LIMIT), GRAD_LIMIT);
            o.y = fminf(fmaxf(gb, -GRAD_LIMIT), GRAD_LIMIT);
            *reinterpret_cast<float2*>(out + (size_t)f * N * 2 + (size_t)n * 2) = o;
        }
    }
}

extern "C" void kernel_launch(void* const* d_in, const int* in_sizes, int n_in,
                              void* d_out, int out_size, void* d_ws, size_t ws_size,
                              hipStream_t stream) {
    const float2* pos = (const float2*)d_in[0];
    const int* edge_index = (const int*)d_in[1];
    const float4* field = (const float4*)d_in[2];
    float* out = (float*)d_out;

    const int N = in_sizes[0] / 2;
    const int E = in_sizes[1] / 2;

    const int* rows = edge_index;      // edge_index[0, :]
    const int* cols = edge_index + E;  // edge_index[1, :]

    // Workspace (ints): bucket_cnt[1024] | bucket_start[1024] | cursor[1024]
    //                   | payload[E]  (~32 MB total)
    int* bucket_cnt = (int*)d_ws;
    int* bucket_start = bucket_cnt + NBUCKET_MAX;
    int* cursor = bucket_start + NBUCKET_MAX;
    unsigned* payload = (unsigned*)(cursor + NBUCKET_MAX);

    const int nbuckets = (N + BSIZE - 1) / BSIZE;       // 977
    const int nblocksE = (E + CHUNK - 1) / CHUNK;       // 977

    hipMemsetAsync(bucket_cnt, 0, NBUCKET_MAX * sizeof(int), stream);

    bucket_count_kernel<<<nblocksE, BTHREADS, 0, stream>>>(rows, bucket_cnt, E,
                                                           nbuckets);
    bucket_scan_kernel<<<1, NBUCKET_MAX, 0, stream>>>(bucket_cnt, bucket_start,
                                                      cursor, nbuckets);
    bucket_scatter_kernel<<<nblocksE, BTHREADS, 0, stream>>>(rows, cols, cursor,
                                                             payload, E, nbuckets);
    bucket_accum_solve_kernel<<<nbuckets, BSIZE, 0, stream>>>(pos, field,
                                                              bucket_start, cursor,
                                                              payload, out, N);
}